// Round 9
// baseline (155.044 us; speedup 1.0000x reference)
//
#include <hip/hip_runtime.h>

// ActivatedAttention: out = transpose(GroupNorm( relu(rope(Q)) @ [relu(rope(K))^T @ relu(V)] )).
// B=4, T=2048, D=1024. y = Q @ (K^T V)  (no softmax -> associativity).
// All GEMMs hi-only bf16 (absmax 0.0234 vs threshold 0.0728, bench-validated).
// Core: 128x128 tile, 4 waves of 64x64 via 2x2 mfma_32x32x16 (2495 TF ceiling, half the
// instruction count of 16x16), BK=64, double-buffered global_load_lds staging with counted
// vmcnt(8) (never drained mid-loop). Proven barrier skeleton (round 7):
//   vmcnt(8); s_barrier; sched_barrier; ds_reads; lgkmcnt(0); sched_barrier; s_barrier; MFMAs
// (sched_barrier after the first s_barrier is REQUIRED: s_barrier is IntrNoMem, compiler
// may otherwise hoist ds_reads above it -> race with other waves' global_load_lds staging.)
// gemm1 fuses table-rope/relu/bf16 epilogue via f32 LDS tile ([n][m] for ALL parts);
// gemm3 fuses GroupNorm + transposed store. Staging swizzle: linear LDS dest,
// XOR-swizzled global source + swizzled ds_read (slot ^= row&7) -> conflict-free.

typedef unsigned short u16;
typedef __attribute__((ext_vector_type(4))) unsigned short u16x4;
typedef __attribute__((ext_vector_type(8))) unsigned short u16x8;
typedef __attribute__((ext_vector_type(4))) float fx4;
typedef __attribute__((ext_vector_type(16))) float f32x16;
typedef __attribute__((ext_vector_type(8))) __bf16 bfx8;

#define TP 129  // epilogue f32 tile pitch

__device__ __forceinline__ u16 f2bh(float v) {  // f32 -> bf16 RNE
  unsigned u = __float_as_uint(v);
  return (u16)((u + 0x7FFFu + ((u >> 16) & 1u)) >> 16);
}
__device__ __forceinline__ f32x16 mfma32(bfx8 a, bfx8 b, f32x16 c) {
  return __builtin_amdgcn_mfma_f32_32x32x16_bf16(a, b, c, 0, 0, 0);
}

__device__ __forceinline__ void gload16(const u16* g, u16* l) {
  __builtin_amdgcn_global_load_lds(
      (const __attribute__((address_space(1))) unsigned int*)(const void*)g,
      (__attribute__((address_space(3))) unsigned int*)(void*)l, 16, 0, 0);
}

// Swizzled LDS read: buffer is [128 rows][8 slots of 16B]; logical slot q of row r
// lives at physical slot q ^ (r&7).
__device__ __forceinline__ bfx8 ldsw(const u16* lds, int row, int slot) {
  const char* p = (const char*)lds + row * 128 + ((slot ^ (row & 7)) << 4);
  return __builtin_bit_cast(bfx8, *reinterpret_cast<const u16x8*>(p));
}

// Stage 128 rows x 64 cols (4 chunks/thread). Linear LDS dest, pre-swizzled global
// source so the read-side XOR matches (both-sides-or-neither).
__device__ __forceinline__ void stage4(const u16* __restrict__ A,
                                       size_t rowBase, int stride, int k0,
                                       u16* lds, int w, int lane) {
#pragma unroll
  for (int i = 0; i < 4; ++i) {
    int c = ((w * 4 + i) << 6) + lane;
    int r = c >> 3, s = c & 7;
    int t = s ^ (r & 7);
    const u16* src = A + (rowBase + (size_t)r) * (size_t)stride + k0 + (t << 3);
    gload16(src, lds + ((w * 4 + i) << 9));
  }
}

// ---- Pipelined hi-only 128x128 GEMM core, BK=64, 32x32x16 MFMA, dbuf staging.
__device__ inline void gemm_core_pipe(const u16* __restrict__ A, size_t aBase, int aStr,
                                      const u16* __restrict__ B, size_t bBase, int bStr, int K,
                                      u16* sA0, u16* sB0, u16* sA1, u16* sB1,
                                      f32x16 acc[2][2], int w, int lane) {
  int wm = (w >> 1) * 64, wn = (w & 1) * 64;
  int ln = lane & 31, hi = lane >> 5;
  stage4(A, aBase, aStr, 0, sA0, w, lane);
  stage4(B, bBase, bStr, 0, sB0, w, lane);
  int NT = K >> 6;
  for (int t = 0; t < NT; ++t) {
    u16* cA = (t & 1) ? sA1 : sA0;
    u16* cB = (t & 1) ? sB1 : sB0;
    if (t + 1 < NT) {
      u16* nA = (t & 1) ? sA0 : sA1;
      u16* nB = (t & 1) ? sB0 : sB1;
      stage4(A, aBase, aStr, (t + 1) << 6, nA, w, lane);
      stage4(B, bBase, bStr, (t + 1) << 6, nB, w, lane);
      asm volatile("s_waitcnt vmcnt(8)" ::: "memory");  // tile-t loads done, 8 in flight
    } else {
      asm volatile("s_waitcnt vmcnt(0)" ::: "memory");
    }
    __builtin_amdgcn_s_barrier();       // tile t resident (all waves)
    __builtin_amdgcn_sched_barrier(0);  // do NOT hoist reads above the barrier (race!)
    bfx8 a[2][4], b[2][4];
#pragma unroll
    for (int rb = 0; rb < 2; ++rb)
#pragma unroll
      for (int ks = 0; ks < 4; ++ks) {
        a[rb][ks] = ldsw(cA, wm + rb * 32 + ln, ks * 2 + hi);
        b[rb][ks] = ldsw(cB, wn + rb * 32 + ln, ks * 2 + hi);
      }
    asm volatile("s_waitcnt lgkmcnt(0)" ::: "memory");  // reads landed in regs
    __builtin_amdgcn_sched_barrier(0);
    __builtin_amdgcn_s_barrier();       // WAR: buffers free; MFMAs overlap next staging
#pragma unroll
    for (int ks = 0; ks < 4; ++ks)
#pragma unroll
      for (int rb = 0; rb < 2; ++rb)
#pragma unroll
        for (int cb = 0; cb < 2; ++cb)
          acc[rb][cb] = mfma32(a[rb][ks], b[cb][ks], acc[rb][cb]);
  }
}

// ---- K0: merged prep: castX (blocks 0..4095), transW (4096..7167), ropetab (7168..15359)
__global__ void k_prep(const float* __restrict__ x, const float* __restrict__ W,
                       u16* __restrict__ xh, u16* __restrict__ WTh,
                       float2* __restrict__ tabTI, float2* __restrict__ tabIT) {
  __shared__ float tile[32][33];
  int bid = blockIdx.x, tid = threadIdx.x;
  if (bid < 4096) {  // cast x -> bf16, 8 elems/thread
    size_t i = ((size_t)bid * 256 + tid) * 8;
    fx4 v0 = *reinterpret_cast<const fx4*>(x + i);
    fx4 v1 = *reinterpret_cast<const fx4*>(x + i + 4);
    u16x8 h;
#pragma unroll
    for (int j = 0; j < 4; ++j) {
      h[j] = f2bh(v0[j]);
      h[4 + j] = f2bh(v1[j]);
    }
    *reinterpret_cast<u16x8*>(xh + i) = h;
  } else if (bid < 7168) {  // transpose W -> WT[3072][1024] bf16
    int idx = bid - 4096;
    int n0 = (idx % 96) * 32, k0 = (idx / 96) * 32;
    int c = tid & 31, r4 = tid >> 5;
#pragma unroll
    for (int it = 0; it < 4; ++it) {
      int r = r4 + it * 8;
      tile[r][c] = W[(size_t)(k0 + r) * 3072 + n0 + c];
    }
    __syncthreads();
#pragma unroll
    for (int it = 0; it < 4; ++it) {
      int r = r4 + it * 8;
      WTh[(size_t)(n0 + r) * 1024 + k0 + c] = f2bh(tile[c][r]);
    }
  } else {  // rope tables: float2(cos,sin)
    int half = (bid - 7168) >> 12;  // 0: tabTI, 1: tabIT
    int idx = ((bid - 7168) & 4095) * 256 + tid;
    int t, i;
    if (half == 0) {
      t = idx >> 9;
      i = idx & 511;
    } else {
      i = idx >> 11;
      t = idx & 2047;
    }
    float invf = exp2f(-(float)i * (13.287712379549449f / 512.f));  // 10000^(-i/512)
    float ang = (float)t * invf, s, c;
    sincosf(ang, &s, &c);
    if (half == 0)
      tabTI[idx] = make_float2(c, s);
    else
      tabIT[idx] = make_float2(c, s);
  }
}

// ---- G1 fused: relu(rope(x@W+b)) -> Qh row-major, Kth/Vth transposed [B][D][T]
__global__ __launch_bounds__(256) void k_gemm1f(const u16* __restrict__ xh,
                                                const u16* __restrict__ WTh,
                                                const float* __restrict__ b_in,
                                                const float2* __restrict__ tabTI,
                                                const float2* __restrict__ tabIT,
                                                u16* __restrict__ Qh, u16* __restrict__ Kth,
                                                u16* __restrict__ Vth) {
  __shared__ __align__(16) float shbuf[128 * TP];  // 66KB; 4x16KB staging buffers alias it
  u16* sA0 = (u16*)shbuf;
  u16* sB0 = sA0 + 128 * 64;
  u16* sA1 = sB0 + 128 * 64;
  u16* sB1 = sA1 + 128 * 64;
  // XCD-chunked swizzle: 1536 blocks = 8 XCD x (8 mt x 24 nt), mt-fastest within chunk.
  int bid = blockIdx.x;
  int xcd = bid & 7, idx = bid >> 3;
  int mt = (xcd << 3) + (idx & 7), nt = idx >> 3;
  int m0 = mt << 7, n0 = nt << 7;
  int tid = threadIdx.x, lane = tid & 63, w = tid >> 6;
  int wm = (w >> 1) * 64, wn = (w & 1) * 64;
  int ln = lane & 31, hi = lane >> 5;
  f32x16 acc[2][2];
#pragma unroll
  for (int i = 0; i < 2; ++i)
#pragma unroll
    for (int j = 0; j < 2; ++j) acc[i][j] = (f32x16)(0.f);

  gemm_core_pipe(xh, (size_t)m0, 1024, WTh, (size_t)n0, 1024, 1024,
                 sA0, sB0, sA1, sB1, acc, w, lane);

  // ---- Epilogue: acc+bias -> f32 LDS tile [n_local][m_local] (ALL parts), then store
  // in output order with vectorized u16x8 stores + table-based rope.
  int part = n0 >> 10;  // 0=Q, 1=K, 2=V (uniform per block)
  float bv[2];
#pragma unroll
  for (int cb = 0; cb < 2; ++cb) bv[cb] = b_in[n0 + wn + cb * 32 + ln];
  __syncthreads();
#pragma unroll
  for (int rb = 0; rb < 2; ++rb)
#pragma unroll
    for (int cb = 0; cb < 2; ++cb)
#pragma unroll
      for (int e = 0; e < 16; ++e) {
        float v = acc[rb][cb][e] + bv[cb];
        int ml = wm + rb * 32 + (e & 3) + 8 * (e >> 2) + 4 * hi;  // C/D row (m74/m101)
        int nl = wn + cb * 32 + ln;                               // C/D col
        shbuf[nl * TP + ml] = v;
      }
  __syncthreads();

  int d0 = n0 - (part << 10);
  int bb = m0 >> 11, tb = m0 & 2047;  // 128-row tiles never cross batch boundary
  int rl0 = tid >> 4;                 // row within tile (per pass: +16)
  int cc = (tid & 15) * 8;            // 8-elem column chunk

  if (part == 2) {  // V: relu only, store [d][t]
#pragma unroll
    for (int pass = 0; pass < 8; ++pass) {
      int rl = rl0 + pass * 16;
      u16x8 o;
#pragma unroll
      for (int j = 0; j < 8; ++j) o[j] = f2bh(fmaxf(shbuf[rl * TP + cc + j], 0.f));
      *reinterpret_cast<u16x8*>(Vth + (((size_t)(bb << 10) + d0 + rl) << 11) + tb + cc) = o;
    }
  } else if (part == 1) {  // K: rope (rows d, d^1) + relu, store [d][t]
#pragma unroll
    for (int pass = 0; pass < 8; ++pass) {
      int rl = rl0 + pass * 16;
      int d = d0 + rl;
      const float2* tp = tabIT + ((size_t)(d >> 1) << 11) + tb + cc;
      const float* e = shbuf + (rl & ~1) * TP + cc;
      const float* oo = shbuf + (rl | 1) * TP + cc;
      int isOdd = d & 1;
      u16x8 o;
#pragma unroll
      for (int j = 0; j < 8; ++j) {
        float2 cs = tp[j];
        float x1 = e[j], x2 = oo[j];
        float v = isOdd ? (x1 * cs.y + x2 * cs.x) : (x1 * cs.x - x2 * cs.y);
        o[j] = f2bh(fmaxf(v, 0.f));
      }
      *reinterpret_cast<u16x8*>(Kth + (((size_t)(bb << 10) + d) << 11) + tb + cc) = o;
    }
  } else {  // Q: rope along d, store [m][d]
#pragma unroll
    for (int pass = 0; pass < 8; ++pass) {
      int rl = rl0 + pass * 16;  // m_local
      int m = m0 + rl, t = m & 2047;
      const float2* tp = tabTI + ((size_t)t << 9) + ((d0 + cc) >> 1);
      u16x8 o;
#pragma unroll
      for (int jp = 0; jp < 4; ++jp) {
        float x1 = shbuf[(cc + 2 * jp) * TP + rl];
        float x2 = shbuf[(cc + 2 * jp + 1) * TP + rl];
        float2 cs = tp[jp];
        o[2 * jp] = f2bh(fmaxf(x1 * cs.x - x2 * cs.y, 0.f));
        o[2 * jp + 1] = f2bh(fmaxf(x1 * cs.y + x2 * cs.x, 0.f));
      }
      *reinterpret_cast<u16x8*>(Qh + ((size_t)m << 10) + d0 + cc) = o;
    }
  }
}

// ---- G2: KtVT[b][n][m] = (K^T V)[m][n], bf16 out
__global__ __launch_bounds__(256) void k_gemm2(const u16* __restrict__ Kth, const u16* __restrict__ Vth,
                                               u16* __restrict__ KtVTh) {
  __shared__ u16 smem[4 * 128 * 64];
  u16* sA0 = smem;
  u16* sB0 = sA0 + 128 * 64;
  u16* sA1 = sB0 + 128 * 64;
  u16* sB1 = sA1 + 128 * 64;
  f32x16 acc[2][2];
#pragma unroll
  for (int i = 0; i < 2; ++i)
#pragma unroll
    for (int j = 0; j < 2; ++j) acc[i][j] = (f32x16)(0.f);
  int b = blockIdx.z;
  int m0 = blockIdx.x << 7, n0 = blockIdx.y << 7;
  int tid = threadIdx.x, lane = tid & 63, w = tid >> 6;
  const u16* Ab = Kth + ((size_t)b << 21);
  const u16* Bb = Vth + ((size_t)b << 21);
  gemm_core_pipe(Ab, (size_t)m0, 2048, Bb, (size_t)n0, 2048, 2048,
                 sA0, sB0, sA1, sB1, acc, w, lane);
  int wm = (w >> 1) * 64, wn = (w & 1) * 64, ln = lane & 31, hi = lane >> 5;
#pragma unroll
  for (int rb = 0; rb < 2; ++rb)
#pragma unroll
    for (int cb = 0; cb < 2; ++cb)
#pragma unroll
      for (int q = 0; q < 4; ++q) {
        u16x4 o;
#pragma unroll
        for (int j = 0; j < 4; ++j) o[j] = f2bh(acc[rb][cb][q * 4 + j]);
        int m = m0 + wm + rb * 32 + q * 8 + hi * 4;  // row=(reg&3)+8*(reg>>2)+4*hi
        int n = n0 + wn + cb * 32 + ln;
        *reinterpret_cast<u16x4*>(KtVTh + ((size_t)b << 20) + ((size_t)n << 10) + m) = o;
      }
}

// ---- G3 fused: y = Q @ KtV, then GroupNorm(32-ch groups) + transposed store out[b][d][t].
// A 32-col C-block = exactly one group across 32 lanes of a half-wave; two-pass mean/var
// via __shfl_xor masks 1..16 (stay within the half).
__global__ __launch_bounds__(256) void k_gemm3g(const u16* __restrict__ Qh, const u16* __restrict__ KtVTh,
                                                const float* __restrict__ gw, const float* __restrict__ gb,
                                                float* __restrict__ out) {
  __shared__ u16 smem[4 * 128 * 64];
  u16* sA0 = smem;
  u16* sB0 = sA0 + 128 * 64;
  u16* sA1 = sB0 + 128 * 64;
  u16* sB1 = sA1 + 128 * 64;
  f32x16 acc[2][2];
#pragma unroll
  for (int i = 0; i < 2; ++i)
#pragma unroll
    for (int j = 0; j < 2; ++j) acc[i][j] = (f32x16)(0.f);
  int b = blockIdx.z;
  int m0 = blockIdx.x << 7, n0 = blockIdx.y << 7;
  int tid = threadIdx.x, lane = tid & 63, w = tid >> 6;
  gemm_core_pipe(Qh, (size_t)(b * 2048 + m0), 1024, KtVTh + ((size_t)b << 20), (size_t)n0, 1024,
                 1024, sA0, sB0, sA1, sB1, acc, w, lane);
  int wm = (w >> 1) * 64, wn = (w & 1) * 64, ln = lane & 31, hi = lane >> 5;
  float wv[2], bvv[2];
#pragma unroll
  for (int cb = 0; cb < 2; ++cb) {
    int n = n0 + wn + cb * 32 + ln;
    wv[cb] = gw[n];
    bvv[cb] = gb[n];
  }
#pragma unroll
  for (int rb = 0; rb < 2; ++rb)
#pragma unroll
    for (int cb = 0; cb < 2; ++cb) {
      float o[16];
#pragma unroll
      for (int e = 0; e < 16; ++e) {
        float v = acc[rb][cb][e];
        float s = v;
#pragma unroll
        for (int mk = 1; mk <= 16; mk <<= 1) s += __shfl_xor(s, mk);
        float mean = s * (1.f / 32.f);
        float d = (v - mean) * (v - mean);
#pragma unroll
        for (int mk = 1; mk <= 16; mk <<= 1) d += __shfl_xor(d, mk);
        float rstd = rsqrtf(d * (1.f / 32.f) + 1e-5f);
        o[e] = (v - mean) * rstd * wv[cb] + bvv[cb];
      }
      int n = n0 + wn + cb * 32 + ln;
#pragma unroll
      for (int q = 0; q < 4; ++q) {
        fx4 ov;
#pragma unroll
        for (int j = 0; j < 4; ++j) ov[j] = o[q * 4 + j];
        int m = m0 + wm + rb * 32 + q * 8 + hi * 4;  // t index, 16B-aligned
        *reinterpret_cast<fx4*>(out + (((size_t)(b << 10) + n) << 11) + m) = ov;
      }
    }
}

extern "C" void kernel_launch(void* const* d_in, const int* in_sizes, int n_in,
                              void* d_out, int out_size, void* d_ws, size_t ws_size,
                              hipStream_t stream) {
  const float* x = (const float*)d_in[0];
  const float* W = (const float*)d_in[1];
  const float* b_in = (const float*)d_in[2];
  const float* gnw = (const float*)d_in[3];
  const float* gnb = (const float*)d_in[4];
  float* out = (float*)d_out;
  char* ws = (char*)d_ws;

  // Workspace (bytes): xh@0(16M) WTh@16M(6M) Qh@22M(16M) Kth@38M(16M) Vth@54M(16M)
  // KtVTh@70M(8M) tabTI@78M(8M) tabIT@86M(8M). Total ~94MB.
  u16* xh = (u16*)(ws + 0);
  u16* WTh = (u16*)(ws + 16777216);
  u16* Qh = (u16*)(ws + 23068672);
  u16* Kth = (u16*)(ws + 39845888);
  u16* Vth = (u16*)(ws + 56623104);
  u16* KtVTh = (u16*)(ws + 73400320);
  float2* tabTI = (float2*)(ws + 81788928);
  float2* tabIT = (float2*)(ws + 90177536);

  k_prep<<<15360, 256, 0, stream>>>(x, W, xh, WTh, tabTI, tabIT);
  k_gemm1f<<<1536, 256, 0, stream>>>(xh, WTh, b_in, tabTI, tabIT, Qh, Kth, Vth);
  k_gemm2<<<dim3(8, 8, 4), 256, 0, stream>>>(Kth, Vth, KtVTh);
  k_gemm3g<<<dim3(16, 8, 4), 256, 0, stream>>>(Qh, KtVTh, gnw, gnb, out);
}

// Round 10
// 140.275 us; speedup vs baseline: 1.1053x; 1.1053x over previous
//
#include <hip/hip_runtime.h>

// ActivatedAttention: out = transpose(GroupNorm( relu(rope(Q)) @ [relu(rope(K))^T @ relu(V)] )).
// B=4, T=2048, D=1024. y = Q @ (K^T V)  (no softmax -> associativity).
// All GEMMs hi-only bf16 (absmax 0.0234 vs threshold 0.0728, bench-validated).
// Core (r7-proven): 128x128 tile, 4 waves of 64x64 via 4x4 mfma_16x16x32, BK=64,
// double-buffered global_load_lds staging, counted vmcnt(8) (never drained mid-loop).
// NOTE (r9 lesson): 32x32 MFMA fragments are >=4-way bank-conflicted with 128B-pitch
// LDS rows (32 lanes, same 16B slot, bank=f(slot) only) -> stick with 16x16 (2 rows/bank).
// Barrier skeleton: vmcnt(8); s_barrier; sched_barrier; ds_reads; lgkmcnt(0);
// sched_barrier; s_barrier; MFMAs (overlap next staging).
// gemm1 fuses table-rope/relu/bf16 epilogue via f32 LDS tile [n][m]; gemm3 fuses
// GroupNorm + transposed store. Staging swizzle: linear LDS dest, XOR-swizzled global
// source + swizzled ds_read (slot ^= row&7) -> conflict-free.

typedef unsigned short u16;
typedef __attribute__((ext_vector_type(8))) unsigned short u16x8;
typedef __attribute__((ext_vector_type(4))) float fx4;
typedef __attribute__((ext_vector_type(8))) __bf16 bfx8;

#define TP 129  // epilogue f32 tile pitch

__device__ __forceinline__ u16 f2bh(float v) {  // f32 -> bf16 RNE
  unsigned u = __float_as_uint(v);
  return (u16)((u + 0x7FFFu + ((u >> 16) & 1u)) >> 16);
}
__device__ __forceinline__ fx4 mfma16(bfx8 a, bfx8 b, fx4 c) {
  return __builtin_amdgcn_mfma_f32_16x16x32_bf16(a, b, c, 0, 0, 0);
}

__device__ __forceinline__ void gload16(const u16* g, u16* l) {
  __builtin_amdgcn_global_load_lds(
      (const __attribute__((address_space(1))) unsigned int*)(const void*)g,
      (__attribute__((address_space(3))) unsigned int*)(void*)l, 16, 0, 0);
}

// Swizzled LDS read: buffer is [128 rows][8 slots of 16B]; logical slot q of row r
// lives at physical slot q ^ (r&7).
__device__ __forceinline__ bfx8 ldsw(const u16* lds, int row, int slot) {
  const char* p = (const char*)lds + row * 128 + ((slot ^ (row & 7)) << 4);
  return __builtin_bit_cast(bfx8, *reinterpret_cast<const u16x8*>(p));
}

// Stage 128 rows x 64 cols (4 chunks/thread). Linear LDS dest, pre-swizzled global
// source so the read-side XOR matches (both-sides-or-neither).
__device__ __forceinline__ void stage4(const u16* __restrict__ A,
                                       size_t rowBase, int stride, int k0,
                                       u16* lds, int w, int lane) {
#pragma unroll
  for (int i = 0; i < 4; ++i) {
    int c = ((w * 4 + i) << 6) + lane;
    int r = c >> 3, s = c & 7;
    int t = s ^ (r & 7);
    const u16* src = A + (rowBase + (size_t)r) * (size_t)stride + k0 + (t << 3);
    gload16(src, lds + ((w * 4 + i) << 9));
  }
}

// ---- Pipelined hi-only 128x128 GEMM core, BK=64, 16x16x32 MFMA, dbuf staging.
__device__ inline void gemm_core_pipe(const u16* __restrict__ A, size_t aBase, int aStr,
                                      const u16* __restrict__ B, size_t bBase, int bStr, int K,
                                      u16* sA0, u16* sB0, u16* sA1, u16* sB1,
                                      fx4 acc[4][4], int w, int lane) {
  int wm = (w >> 1) * 64, wn = (w & 1) * 64;
  int lr = lane & 15, lk = lane >> 4;
  stage4(A, aBase, aStr, 0, sA0, w, lane);
  stage4(B, bBase, bStr, 0, sB0, w, lane);
  int NT = K >> 6;
  for (int t = 0; t < NT; ++t) {
    u16* cA = (t & 1) ? sA1 : sA0;
    u16* cB = (t & 1) ? sB1 : sB0;
    if (t + 1 < NT) {
      u16* nA = (t & 1) ? sA0 : sA1;
      u16* nB = (t & 1) ? sB0 : sB1;
      stage4(A, aBase, aStr, (t + 1) << 6, nA, w, lane);
      stage4(B, bBase, bStr, (t + 1) << 6, nB, w, lane);
      asm volatile("s_waitcnt vmcnt(8)" ::: "memory");  // tile-t loads done, 8 in flight
    } else {
      asm volatile("s_waitcnt vmcnt(0)" ::: "memory");
    }
    __builtin_amdgcn_s_barrier();       // tile t resident (all waves)
    __builtin_amdgcn_sched_barrier(0);  // do NOT hoist reads above the barrier (race!)
    bfx8 a[8], b[8];
#pragma unroll
    for (int h = 0; h < 2; ++h)
#pragma unroll
      for (int i = 0; i < 4; ++i) {
        a[h * 4 + i] = ldsw(cA, wm + i * 16 + lr, h * 4 + lk);
        b[h * 4 + i] = ldsw(cB, wn + i * 16 + lr, h * 4 + lk);
      }
    asm volatile("s_waitcnt lgkmcnt(0)" ::: "memory");  // reads landed in regs
    __builtin_amdgcn_sched_barrier(0);
    __builtin_amdgcn_s_barrier();       // WAR: buffers free; MFMAs overlap next staging
#pragma unroll
    for (int h = 0; h < 2; ++h)
#pragma unroll
      for (int mi = 0; mi < 4; ++mi)
#pragma unroll
        for (int ni = 0; ni < 4; ++ni)
          acc[mi][ni] = mfma16(a[h * 4 + mi], b[h * 4 + ni], acc[mi][ni]);
  }
}

// ---- K0: merged prep: castX (blocks 0..4095), transW (4096..7167), ropetab (7168..15359)
__global__ void k_prep(const float* __restrict__ x, const float* __restrict__ W,
                       u16* __restrict__ xh, u16* __restrict__ WTh,
                       float2* __restrict__ tabTI, float2* __restrict__ tabIT) {
  __shared__ float tile[32][33];
  int bid = blockIdx.x, tid = threadIdx.x;
  if (bid < 4096) {  // cast x -> bf16, 8 elems/thread
    size_t i = ((size_t)bid * 256 + tid) * 8;
    fx4 v0 = *reinterpret_cast<const fx4*>(x + i);
    fx4 v1 = *reinterpret_cast<const fx4*>(x + i + 4);
    u16x8 h;
#pragma unroll
    for (int j = 0; j < 4; ++j) {
      h[j] = f2bh(v0[j]);
      h[4 + j] = f2bh(v1[j]);
    }
    *reinterpret_cast<u16x8*>(xh + i) = h;
  } else if (bid < 7168) {  // transpose W -> WT[3072][1024] bf16
    int idx = bid - 4096;
    int n0 = (idx % 96) * 32, k0 = (idx / 96) * 32;
    int c = tid & 31, r4 = tid >> 5;
#pragma unroll
    for (int it = 0; it < 4; ++it) {
      int r = r4 + it * 8;
      tile[r][c] = W[(size_t)(k0 + r) * 3072 + n0 + c];
    }
    __syncthreads();
#pragma unroll
    for (int it = 0; it < 4; ++it) {
      int r = r4 + it * 8;
      WTh[(size_t)(n0 + r) * 1024 + k0 + c] = f2bh(tile[c][r]);
    }
  } else {  // rope tables: float2(cos,sin)
    int half = (bid - 7168) >> 12;  // 0: tabTI, 1: tabIT
    int idx = ((bid - 7168) & 4095) * 256 + tid;
    int t, i;
    if (half == 0) {
      t = idx >> 9;
      i = idx & 511;
    } else {
      i = idx >> 11;
      t = idx & 2047;
    }
    float invf = exp2f(-(float)i * (13.287712379549449f / 512.f));  // 10000^(-i/512)
    float ang = (float)t * invf, s, c;
    sincosf(ang, &s, &c);
    if (half == 0)
      tabTI[idx] = make_float2(c, s);
    else
      tabIT[idx] = make_float2(c, s);
  }
}

// ---- G1 fused: relu(rope(x@W+b)) -> Qh row-major, Kth/Vth transposed [B][D][T]
__global__ __launch_bounds__(256) void k_gemm1f(const u16* __restrict__ xh,
                                                const u16* __restrict__ WTh,
                                                const float* __restrict__ b_in,
                                                const float2* __restrict__ tabTI,
                                                const float2* __restrict__ tabIT,
                                                u16* __restrict__ Qh, u16* __restrict__ Kth,
                                                u16* __restrict__ Vth) {
  __shared__ __align__(16) float shbuf[128 * TP];  // 66KB; 4x16KB staging buffers alias it
  u16* sA0 = (u16*)shbuf;
  u16* sB0 = sA0 + 128 * 64;
  u16* sA1 = sB0 + 128 * 64;
  u16* sB1 = sA1 + 128 * 64;
  // XCD-chunked swizzle: 1536 blocks = 8 XCD x (8 mt x 24 nt), mt-fastest within chunk.
  int bid = blockIdx.x;
  int xcd = bid & 7, idx = bid >> 3;
  int mt = (xcd << 3) + (idx & 7), nt = idx >> 3;
  int m0 = mt << 7, n0 = nt << 7;
  int tid = threadIdx.x, lane = tid & 63, w = tid >> 6;
  int wm = (w >> 1) * 64, wn = (w & 1) * 64;
  int lr = lane & 15, lk = lane >> 4;
  fx4 acc[4][4];
#pragma unroll
  for (int i = 0; i < 4; ++i)
#pragma unroll
    for (int j = 0; j < 4; ++j) acc[i][j] = fx4{0.f, 0.f, 0.f, 0.f};

  gemm_core_pipe(xh, (size_t)m0, 1024, WTh, (size_t)n0, 1024, 1024,
                 sA0, sB0, sA1, sB1, acc, w, lane);

  // ---- Epilogue: acc+bias -> f32 LDS tile [n_local][m_local], then store in output
  // order with vectorized u16x8 stores + table-based rope.
  float bv[4];
#pragma unroll
  for (int ni = 0; ni < 4; ++ni) bv[ni] = b_in[n0 + wn + ni * 16 + lr];
  __syncthreads();  // all LDS reads of staging done before overwrite
#pragma unroll
  for (int mi = 0; mi < 4; ++mi)
#pragma unroll
    for (int ni = 0; ni < 4; ++ni)
#pragma unroll
      for (int r = 0; r < 4; ++r)
        shbuf[(wn + ni * 16 + lr) * TP + wm + mi * 16 + lk * 4 + r] = acc[mi][ni][r] + bv[ni];
  __syncthreads();

  int part = n0 >> 10;       // 0=Q, 1=K, 2=V (uniform per block)
  int d0 = n0 - (part << 10);
  int bb = m0 >> 11, tb = m0 & 2047;  // 128-row tiles never cross batch boundary
  int rl0 = tid >> 4;        // row within tile (per pass: +16)
  int cc = (tid & 15) * 8;   // 8-elem column chunk

  if (part == 2) {           // V: relu only, store [d][t]
#pragma unroll
    for (int pass = 0; pass < 8; ++pass) {
      int rl = rl0 + pass * 16;
      u16x8 o;
#pragma unroll
      for (int j = 0; j < 8; ++j) o[j] = f2bh(fmaxf(shbuf[rl * TP + cc + j], 0.f));
      *reinterpret_cast<u16x8*>(Vth + (((size_t)(bb << 10) + d0 + rl) << 11) + tb + cc) = o;
    }
  } else if (part == 1) {    // K: rope (rows d, d^1) + relu, store [d][t]
#pragma unroll
    for (int pass = 0; pass < 8; ++pass) {
      int rl = rl0 + pass * 16;
      int d = d0 + rl;
      const float2* tp = tabIT + ((size_t)(d >> 1) << 11) + tb + cc;
      const float* e = shbuf + (rl & ~1) * TP + cc;   // even row
      const float* oo = shbuf + (rl | 1) * TP + cc;   // odd row
      int isOdd = d & 1;
      u16x8 o;
#pragma unroll
      for (int j = 0; j < 8; ++j) {
        float2 cs = tp[j];
        float x1 = e[j], x2 = oo[j];
        float v = isOdd ? (x1 * cs.y + x2 * cs.x) : (x1 * cs.x - x2 * cs.y);
        o[j] = f2bh(fmaxf(v, 0.f));
      }
      *reinterpret_cast<u16x8*>(Kth + (((size_t)(bb << 10) + d) << 11) + tb + cc) = o;
    }
  } else {                   // Q: rope along d, store [m][d]
#pragma unroll
    for (int pass = 0; pass < 8; ++pass) {
      int rl = rl0 + pass * 16;  // m_local
      int m = m0 + rl, t = m & 2047;
      const float2* tp = tabTI + ((size_t)t << 9) + ((d0 + cc) >> 1);
      u16x8 o;
#pragma unroll
      for (int jp = 0; jp < 4; ++jp) {
        float x1 = shbuf[(cc + 2 * jp) * TP + rl];
        float x2 = shbuf[(cc + 2 * jp + 1) * TP + rl];
        float2 cs = tp[jp];
        o[2 * jp] = f2bh(fmaxf(x1 * cs.x - x2 * cs.y, 0.f));
        o[2 * jp + 1] = f2bh(fmaxf(x1 * cs.y + x2 * cs.x, 0.f));
      }
      *reinterpret_cast<u16x8*>(Qh + ((size_t)m << 10) + d0 + cc) = o;
    }
  }
}

// ---- G2: KtVT[b][n][m] = (K^T V)[m][n], bf16 out. 256 blocks, 2 XCDs per batch.
__global__ __launch_bounds__(256) void k_gemm2(const u16* __restrict__ Kth, const u16* __restrict__ Vth,
                                               u16* __restrict__ KtVTh) {
  __shared__ u16 smem[4 * 128 * 64];
  u16* sA0 = smem;
  u16* sB0 = sA0 + 128 * 64;
  u16* sA1 = sB0 + 128 * 64;
  u16* sB1 = sA1 + 128 * 64;
  fx4 acc[4][4];
#pragma unroll
  for (int i = 0; i < 4; ++i)
#pragma unroll
    for (int j = 0; j < 4; ++j) acc[i][j] = fx4{0.f, 0.f, 0.f, 0.f};
  // XCD swizzle: xcd owns (b = xcd>>1, 4 mt x 8 nt), mt-fastest -> A slice 2MB resident.
  int bid = blockIdx.x;
  int xcd = bid & 7, idx = bid >> 3;
  int b = xcd >> 1;
  int mt = (xcd & 1) * 4 + (idx & 3), nt = idx >> 2;
  int m0 = mt << 7, n0 = nt << 7;
  int tid = threadIdx.x, lane = tid & 63, w = tid >> 6;
  const u16* Ab = Kth + ((size_t)b << 21);
  const u16* Bb = Vth + ((size_t)b << 21);
  gemm_core_pipe(Ab, (size_t)m0, 2048, Bb, (size_t)n0, 2048, 2048,
                 sA0, sB0, sA1, sB1, acc, w, lane);
  int wm = (w >> 1) * 64, wn = (w & 1) * 64, lr = lane & 15, lk = lane >> 4;
#pragma unroll
  for (int mi = 0; mi < 4; ++mi)
#pragma unroll
    for (int ni = 0; ni < 4; ++ni)
#pragma unroll
      for (int r = 0; r < 4; ++r) {
        int m = m0 + wm + mi * 16 + lk * 4 + r;
        int n = n0 + wn + ni * 16 + lr;
        KtVTh[((size_t)b << 20) + ((size_t)n << 10) + m] = f2bh(acc[mi][ni][r]);
      }
}

// ---- G3 fused: y = Q @ KtV, then GroupNorm(32-ch groups) + transposed store out[b][d][t].
// 512 blocks, 2 XCDs per batch.
__global__ __launch_bounds__(256) void k_gemm3g(const u16* __restrict__ Qh, const u16* __restrict__ KtVTh,
                                                const float* __restrict__ gw, const float* __restrict__ gb,
                                                float* __restrict__ out) {
  __shared__ u16 smem[4 * 128 * 64];
  u16* sA0 = smem;
  u16* sB0 = sA0 + 128 * 64;
  u16* sA1 = sB0 + 128 * 64;
  u16* sB1 = sA1 + 128 * 64;
  fx4 acc[4][4];
#pragma unroll
  for (int i = 0; i < 4; ++i)
#pragma unroll
    for (int j = 0; j < 4; ++j) acc[i][j] = fx4{0.f, 0.f, 0.f, 0.f};
  int bid = blockIdx.x;
  int xcd = bid & 7, idx = bid >> 3;  // idx 0..63
  int b = xcd >> 1;
  int mt = (xcd & 1) * 8 + (idx & 7), nt = idx >> 3;
  int m0 = mt << 7, n0 = nt << 7;
  int tid = threadIdx.x, lane = tid & 63, w = tid >> 6;
  gemm_core_pipe(Qh, (size_t)(b * 2048 + m0), 1024, KtVTh + ((size_t)b << 20), (size_t)n0, 1024,
                 1024, sA0, sB0, sA1, sB1, acc, w, lane);
  int wm = (w >> 1) * 64, wn = (w & 1) * 64, lr = lane & 15, lk = lane >> 4;
  float wv[4], bvv[4];
#pragma unroll
  for (int ni = 0; ni < 4; ++ni) {
    int n = n0 + wn + ni * 16 + lr;
    wv[ni] = gw[n];
    bvv[ni] = gb[n];
  }
#pragma unroll
  for (int mi = 0; mi < 4; ++mi) {
    fx4 o0, o1, o2, o3;
#pragma unroll
    for (int r = 0; r < 4; ++r) {
      float v0 = acc[mi][0][r], v1 = acc[mi][1][r], v2 = acc[mi][2][r], v3 = acc[mi][3][r];
      float sA2 = v0 + v1, sB2 = v2 + v3;
#pragma unroll
      for (int mk = 1; mk <= 8; mk <<= 1) {
        sA2 += __shfl_xor(sA2, mk);
        sB2 += __shfl_xor(sB2, mk);
      }
      float mA = sA2 * (1.f / 32.f), mB = sB2 * (1.f / 32.f);
      float dA = (v0 - mA) * (v0 - mA) + (v1 - mA) * (v1 - mA);
      float dB = (v2 - mB) * (v2 - mB) + (v3 - mB) * (v3 - mB);
#pragma unroll
      for (int mk = 1; mk <= 8; mk <<= 1) {
        dA += __shfl_xor(dA, mk);
        dB += __shfl_xor(dB, mk);
      }
      float rA = rsqrtf(dA * (1.f / 32.f) + 1e-5f);
      float rB = rsqrtf(dB * (1.f / 32.f) + 1e-5f);
      o0[r] = (v0 - mA) * rA * wv[0] + bvv[0];
      o1[r] = (v1 - mA) * rA * wv[1] + bvv[1];
      o2[r] = (v2 - mB) * rB * wv[2] + bvv[2];
      o3[r] = (v3 - mB) * rB * wv[3] + bvv[3];
    }
    int mbase = m0 + wm + mi * 16 + lk * 4;  // t index, 16B-aligned
#pragma unroll
    for (int ni = 0; ni < 4; ++ni) {
      int n = n0 + wn + ni * 16 + lr;
      fx4 ov = (ni == 0) ? o0 : (ni == 1) ? o1 : (ni == 2) ? o2 : o3;
      *reinterpret_cast<fx4*>(out + (((size_t)(b << 10) + n) << 11) + mbase) = ov;
    }
  }
}

extern "C" void kernel_launch(void* const* d_in, const int* in_sizes, int n_in,
                              void* d_out, int out_size, void* d_ws, size_t ws_size,
                              hipStream_t stream) {
  const float* x = (const float*)d_in[0];
  const float* W = (const float*)d_in[1];
  const float* b_in = (const float*)d_in[2];
  const float* gnw = (const float*)d_in[3];
  const float* gnb = (const float*)d_in[4];
  float* out = (float*)d_out;
  char* ws = (char*)d_ws;

  // Workspace (bytes): xh@0(16M) WTh@16M(6M) Qh@22M(16M) Kth@38M(16M) Vth@54M(16M)
  // KtVTh@70M(8M) tabTI@78M(8M) tabIT@86M(8M). Total ~94MB.
  u16* xh = (u16*)(ws + 0);
  u16* WTh = (u16*)(ws + 16777216);
  u16* Qh = (u16*)(ws + 23068672);
  u16* Kth = (u16*)(ws + 39845888);
  u16* Vth = (u16*)(ws + 56623104);
  u16* KtVTh = (u16*)(ws + 73400320);
  float2* tabTI = (float2*)(ws + 81788928);
  float2* tabIT = (float2*)(ws + 90177536);

  k_prep<<<15360, 256, 0, stream>>>(x, W, xh, WTh, tabTI, tabIT);
  k_gemm1f<<<1536, 256, 0, stream>>>(xh, WTh, b_in, tabTI, tabIT, Qh, Kth, Vth);
  k_gemm2<<<256, 256, 0, stream>>>(Kth, Vth, KtVTh);
  k_gemm3g<<<512, 256, 0, stream>>>(Qh, KtVTh, gnw, gnb, out);
}